// Round 1
// baseline (817.369 us; speedup 1.0000x reference)
//
#include <hip/hip_runtime.h>
#include <hip/hip_bf16.h>
#include <math.h>

#define T_TOK 4096
#define D_DIM 1024
#define I_DIM 4096
#define E_EXP 8
#define MAX_TILES 48

typedef __attribute__((ext_vector_type(8))) short bf16x8;
typedef __attribute__((ext_vector_type(4))) float f32x4;

__device__ __forceinline__ unsigned short f2bf(float x) {
    unsigned int u = __float_as_uint(x);
    u += 0x7fffu + ((u >> 16) & 1u);   // RNE
    return (unsigned short)(u >> 16);
}

// async global->LDS, 16B per lane; lds dest = wave-uniform base + lane*16
__device__ __forceinline__ void glds16(const unsigned short* g, unsigned short* l) {
    __builtin_amdgcn_global_load_lds(
        (const __attribute__((address_space(1))) unsigned int*)g,
        (__attribute__((address_space(3))) unsigned int*)(unsigned int)(unsigned long long)(void*)l,
        16, 0, 0);
}

#define VMWAIT4 asm volatile("s_waitcnt vmcnt(4)" ::: "memory")
#define VMWAIT3 asm volatile("s_waitcnt vmcnt(3)" ::: "memory")
#define VMWAIT0 asm volatile("s_waitcnt vmcnt(0)" ::: "memory")

__device__ __forceinline__ void bar() {
    asm volatile("" ::: "memory");
    __builtin_amdgcn_s_barrier();
    asm volatile("" ::: "memory");
}

// ---------------- gate: logits (fp32 exact), softmax, top-2, weights ----------------
__global__ void gate_kernel(const float* __restrict__ h, const float* __restrict__ gw,
                            int* __restrict__ counts, int* __restrict__ sel,
                            float* __restrict__ wgt) {
    int t = blockIdx.x;
    int tid = threadIdx.x;
    float acc[E_EXP];
#pragma unroll
    for (int e = 0; e < E_EXP; e++) acc[e] = 0.f;
    const float* hr = h + (size_t)t * D_DIM;
    for (int d = tid; d < D_DIM; d += 256) {
        float hv = hr[d];
#pragma unroll
        for (int e = 0; e < E_EXP; e++) acc[e] += hv * gw[e * D_DIM + d];
    }
#pragma unroll
    for (int e = 0; e < E_EXP; e++)
        for (int off = 32; off > 0; off >>= 1) acc[e] += __shfl_down(acc[e], off, 64);
    __shared__ float red[4][E_EXP];
    int wave = tid >> 6, lane = tid & 63;
    if (lane == 0) {
#pragma unroll
        for (int e = 0; e < E_EXP; e++) red[wave][e] = acc[e];
    }
    __syncthreads();
    if (tid == 0) {
        float lg[E_EXP];
#pragma unroll
        for (int e = 0; e < E_EXP; e++) lg[e] = red[0][e] + red[1][e] + red[2][e] + red[3][e];
        float mx = lg[0];
#pragma unroll
        for (int e = 1; e < E_EXP; e++) mx = fmaxf(mx, lg[e]);
        float p[E_EXP];
#pragma unroll
        for (int e = 0; e < E_EXP; e++) p[e] = expf(lg[e] - mx);
        int i0 = 0; float b0 = p[0];
#pragma unroll
        for (int e = 1; e < E_EXP; e++) if (p[e] > b0) { b0 = p[e]; i0 = e; }
        int i1 = -1; float b1v = -1.f;
#pragma unroll
        for (int e = 0; e < E_EXP; e++) if (e != i0 && p[e] > b1v) { b1v = p[e]; i1 = e; }
        float den = b0 + b1v;
        sel[2 * t] = i0; sel[2 * t + 1] = i1;
        wgt[2 * t] = b0 / den; wgt[2 * t + 1] = b1v / den;
        atomicAdd(&counts[i0], 1);
        atomicAdd(&counts[i1], 1);
    }
}

// ---------------- offsets + cursors + aux loss + compacted tile table (BM=256) ----------------
__global__ void offsets_kernel(const int* __restrict__ counts, int* __restrict__ offs,
                               int* __restrict__ cursors, float* __restrict__ aux_out,
                               int* __restrict__ tile_e, int* __restrict__ tile_m,
                               int* __restrict__ ntiles) {
    if (blockIdx.x == 0 && threadIdx.x == 0) {
        int off = 0; float aux = 0.f; int nt = 0;
        for (int e = 0; e < E_EXP; e++) {
            offs[e] = off; off += counts[e]; cursors[e] = 0;
            float u = (float)counts[e] / (float)T_TOK;
            float d = u - 1.0f / (float)E_EXP;
            aux += d * d;
            for (int m0 = 0; m0 < counts[e]; m0 += 256) {
                tile_e[nt] = e; tile_m[nt] = m0; nt++;
            }
        }
        ntiles[0] = nt;
        aux_out[0] = aux / (float)E_EXP;
    }
}

// ---------------- scatter tokens into per-expert segments ----------------
__global__ void scatter_kernel(const int* __restrict__ sel, const float* __restrict__ wgt,
                               const int* __restrict__ offs, int* __restrict__ cursors,
                               int* __restrict__ tok_list, float* __restrict__ tok_w,
                               int* __restrict__ slot_of) {
    int t = blockIdx.x * 256 + threadIdx.x;
    if (t >= T_TOK) return;
#pragma unroll
    for (int k = 0; k < 2; k++) {
        int e = sel[2 * t + k];
        int pos = atomicAdd(&cursors[e], 1);
        int idx = offs[e] + pos;
        tok_list[idx] = t;
        tok_w[idx] = wgt[2 * t + k];
        slot_of[2 * t + k] = idx;
    }
}

// ---------------- H fp32 -> bf16 ----------------
__global__ void cvtH_kernel(const float* __restrict__ src, unsigned short* __restrict__ dst) {
    size_t i = ((size_t)blockIdx.x * 256 + threadIdx.x) * 8;
    float4 a = *(const float4*)(src + i);
    float4 b = *(const float4*)(src + i + 4);
    union { unsigned short u[8]; uint4 v; } o;
    o.u[0] = f2bf(a.x); o.u[1] = f2bf(a.y); o.u[2] = f2bf(a.z); o.u[3] = f2bf(a.w);
    o.u[4] = f2bf(b.x); o.u[5] = f2bf(b.y); o.u[6] = f2bf(b.z); o.u[7] = f2bf(b.w);
    *(uint4*)(dst + i) = o.v;
}

// ---------------- weight transpose + fp32->bf16: (E,R,C) -> (E,C,R) ----------------
__global__ void transpose_cvt_kernel(const float* __restrict__ src, unsigned short* __restrict__ dst,
                                     int R, int C) {
    __shared__ float tile[32][33];
    int e = blockIdx.z;
    const float* s = src + (size_t)e * R * C;
    unsigned short* d = dst + (size_t)e * R * C;
    int c0 = blockIdx.x * 32, r0 = blockIdx.y * 32;
    int tx = threadIdx.x, ty = threadIdx.y;
#pragma unroll
    for (int j = 0; j < 4; j++)
        tile[ty + 8 * j][tx] = s[(size_t)(r0 + ty + 8 * j) * C + c0 + tx];
    __syncthreads();
#pragma unroll
    for (int j = 0; j < 4; j++)
        d[(size_t)(c0 + ty + 8 * j) * R + r0 + tx] = f2bf(tile[tx][ty + 8 * j]);
}

// ---------------- grouped GEMM, 256xBN tile, 8 waves, 4-deep BK=32 LDS ring, counted vmcnt ----
// MODE 0: mid = gelu(gather(Hbf) @ W1t^T + b1)       -> bf16 mid (2T x I), BN=256
// MODE 1: slotbuf = tok_w * (mid @ W2t^T + b2)       -> fp32 slotbuf (2T x D), BN=128
template <int MODE>
__launch_bounds__(512, 2)
__global__ void moe_gemm_kernel(const unsigned short* __restrict__ Abase,
                                const unsigned short* __restrict__ Bt,
                                const float* __restrict__ bias,
                                const int* __restrict__ counts, const int* __restrict__ offs,
                                const int* __restrict__ tile_e, const int* __restrict__ tile_m,
                                const int* __restrict__ ntiles,
                                const int* __restrict__ tok_list, const float* __restrict__ tok_w,
                                unsigned short* __restrict__ midout, float* __restrict__ slotbuf) {
    constexpr int K  = (MODE == 0) ? D_DIM : I_DIM;
    constexpr int N  = (MODE == 0) ? I_DIM : D_DIM;
    constexpr int BN = (MODE == 0) ? 256 : 128;
    constexpr int NJ = BN / 64;    // frag-cols per wave (4 or 2)
    constexpr int SB = BN / 128;   // B stage calls per wave per tile (2 or 1)
    constexpr int NT = K / 32;     // K-tiles

    // 4-deep ring: computing tiles 2i,2i+1 while staging 2i+2,2i+3 -> disjoint buffers
    __shared__ __align__(16) unsigned short lA[4][256 * 32];
    __shared__ __align__(16) unsigned short lB[4][BN * 32];

    // bijective XCD chunk remap: consecutive work-ids (same A panel / expert) stay on one XCD
    const int nwg  = gridDim.x * gridDim.y;
    const int flat = blockIdx.y * gridDim.x + blockIdx.x;
    const int q8 = nwg >> 3, r8 = nwg & 7;
    const int xcd = flat & 7, pos = flat >> 3;
    const int id2 = (xcd < r8 ? xcd * (q8 + 1) : r8 * (q8 + 1) + (xcd - r8) * q8) + pos;
    const int tix = id2 / gridDim.y;
    const int nb  = id2 % gridDim.y;
    if (tix >= ntiles[0]) return;

    const int e   = tile_e[tix];
    const int m0  = tile_m[tix];
    const int Ne  = counts[e];
    const int seg = offs[e];
    const int n0  = nb * BN;

    const int tid  = threadIdx.x;
    const int w    = tid >> 6;
    const int lane = tid & 63;
    const int quad = lane >> 4;
    const int l15  = lane & 15;
    const int wm   = (w >> 2) * 128;        // wave row offset (2 wave-rows)
    const int wn   = (w & 3) * (NJ * 16);   // wave col offset (4 wave-cols)

    // ---- staging pointers: per-lane global src; LDS dest is wave-uniform (HW adds lane*16)
    const int lrow = lane >> 2;        // 0..15 rows per glds call
    const int lcol = (lane & 3) * 8;   // shorts
    const unsigned short* gA0;
    const unsigned short* gA1;
    {
        int mr0 = m0 + w * 32 + lrow;
        int mr1 = mr0 + 16;
        int c0 = (mr0 < Ne) ? mr0 : 0;
        int c1 = (mr1 < Ne) ? mr1 : 0;
        size_t r0, r1;
        if (MODE == 0) { r0 = (size_t)tok_list[seg + c0] * K; r1 = (size_t)tok_list[seg + c1] * K; }
        else           { r0 = (size_t)(seg + c0) * K;         r1 = (size_t)(seg + c1) * K; }
        gA0 = Abase + r0 + lcol;
        gA1 = Abase + r1 + lcol;
    }
    const unsigned short* Bte = Bt + (size_t)e * N * K;
    const unsigned short* gB0 = Bte + (size_t)(n0 + w * (16 * SB) + lrow) * K + lcol;
    const unsigned short* gB1 = gB0 + (size_t)16 * K;   // MODE0 only

    auto ISSUE = [&](int kt2) {
        const int b2  = kt2 & 3;
        const int off = kt2 * 32;
        glds16(gA0 + off, &lA[b2][w * 1024]);
        glds16(gA1 + off, &lA[b2][w * 1024 + 512]);
        glds16(gB0 + off, &lB[b2][w * (SB * 512)]);
        if constexpr (MODE == 0) glds16(gB1 + off, &lB[b2][w * 1024 + 512]);
    };

    f32x4 acc[8][NJ];
#pragma unroll
    for (int a = 0; a < 8; a++)
#pragma unroll
        for (int j = 0; j < NJ; j++) acc[a][j] = (f32x4){0.f, 0.f, 0.f, 0.f};

    const int sc = quad * 8;   // K-subslice column (shorts)

    auto TILE = [&](int kt2) {
        const unsigned short* LA = lA[kt2 & 3];
        const unsigned short* LB = lB[kt2 & 3];
        bf16x8 bv[NJ];
#pragma unroll
        for (int j = 0; j < NJ; j++)
            bv[j] = *(const bf16x8*)&LB[(wn + j * 16 + l15) * 32 + sc];
#pragma unroll
        for (int pm = 0; pm < 2; pm++) {
            bf16x8 av[4];
#pragma unroll
            for (int ii = 0; ii < 4; ii++)
                av[ii] = *(const bf16x8*)&LA[(wm + pm * 64 + ii * 16 + l15) * 32 + sc];
            __builtin_amdgcn_s_setprio(1);
#pragma unroll
            for (int ii = 0; ii < 4; ii++)
#pragma unroll
                for (int j = 0; j < NJ; j++)
                    acc[pm * 4 + ii][j] = __builtin_amdgcn_mfma_f32_16x16x32_bf16(
                        av[ii], bv[j], acc[pm * 4 + ii][j], 0, 0, 0);
            __builtin_amdgcn_s_setprio(0);
        }
    };

    // prologue: stage tiles 0,1
    ISSUE(0);
    ISSUE(1);

    for (int kt = 0; kt < NT; kt += 2) {
        // wait: tile kt landed (leaves tile kt+1's loads in flight)
        if constexpr (MODE == 0) { VMWAIT4; } else { VMWAIT3; }
        bar();
        if (kt + 2 < NT) ISSUE(kt + 2);
        TILE(kt);
        // wait: tile kt+1 landed (leaves tile kt+2's loads in flight); drain only at the very end
        if (kt + 3 < NT) {
            if constexpr (MODE == 0) { VMWAIT4; } else { VMWAIT3; }
        } else {
            VMWAIT0;
        }
        bar();
        if (kt + 3 < NT) ISSUE(kt + 3);
        TILE(kt + 1);
    }

    // ---- epilogue ----
    const float* be = bias + (size_t)e * N;
#pragma unroll
    for (int a = 0; a < 8; a++) {
        const int mbase = m0 + wm + (a >> 2) * 64 + (a & 3) * 16 + quad * 4;
#pragma unroll
        for (int j = 0; j < NJ; j++) {
            const int n = n0 + wn + j * 16 + l15;
            const float bvl = be[n];
#pragma unroll
            for (int r = 0; r < 4; r++) {
                const int m = mbase + r;
                if (m < Ne) {
                    float v = acc[a][j][r] + bvl;
                    if (MODE == 0) {
                        v = 0.5f * v * (1.0f + erff(v * 0.70710678118654752f));
                        midout[(size_t)(seg + m) * N + n] = f2bf(v);
                    } else {
                        slotbuf[(size_t)(seg + m) * N + n] = tok_w[seg + m] * v;
                    }
                }
            }
        }
    }
}

// ---------------- residual + mask + LayerNorm ----------------
__global__ void ln_kernel(const float* __restrict__ hs, const float* __restrict__ mask,
                          const float* __restrict__ slotbuf, const int* __restrict__ slot_of,
                          const float* __restrict__ gamma, const float* __restrict__ beta,
                          float* __restrict__ outp) {
    int t = blockIdx.x, tid = threadIdx.x;
    int s0 = slot_of[2 * t], s1 = slot_of[2 * t + 1];
    float mk = mask[t];
    const float4* hr = (const float4*)(hs + (size_t)t * D_DIM);
    const float4* p0 = (const float4*)(slotbuf + (size_t)s0 * D_DIM);
    const float4* p1 = (const float4*)(slotbuf + (size_t)s1 * D_DIM);
    float4 hv = hr[tid], a = p0[tid], b = p1[tid];
    float x0 = hv.x + mk * (a.x + b.x);
    float x1 = hv.y + mk * (a.y + b.y);
    float x2 = hv.z + mk * (a.z + b.z);
    float x3 = hv.w + mk * (a.w + b.w);
    float sum = x0 + x1 + x2 + x3;
    float sq = x0 * x0 + x1 * x1 + x2 * x2 + x3 * x3;
    for (int off = 32; off > 0; off >>= 1) {
        sum += __shfl_down(sum, off, 64);
        sq += __shfl_down(sq, off, 64);
    }
    __shared__ float rsum[4], rsq[4];
    __shared__ float mu_s, rstd_s;
    int wave = tid >> 6, lane = tid & 63;
    if (lane == 0) { rsum[wave] = sum; rsq[wave] = sq; }
    __syncthreads();
    if (tid == 0) {
        float s = rsum[0] + rsum[1] + rsum[2] + rsum[3];
        float q = rsq[0] + rsq[1] + rsq[2] + rsq[3];
        float mu = s / (float)D_DIM;
        float var = q / (float)D_DIM - mu * mu;
        mu_s = mu; rstd_s = rsqrtf(var + 1e-5f);
    }
    __syncthreads();
    float mu = mu_s, rstd = rstd_s;
    const float4* g4 = (const float4*)gamma;
    const float4* b4 = (const float4*)beta;
    float4 g = g4[tid], bb = b4[tid];
    float4 o;
    o.x = (x0 - mu) * rstd * g.x + bb.x;
    o.y = (x1 - mu) * rstd * g.y + bb.y;
    o.z = (x2 - mu) * rstd * g.z + bb.z;
    o.w = (x3 - mu) * rstd * g.w + bb.w;
    ((float4*)(outp + (size_t)t * D_DIM))[tid] = o;
}

extern "C" void kernel_launch(void* const* d_in, const int* in_sizes, int n_in,
                              void* d_out, int out_size, void* d_ws, size_t ws_size,
                              hipStream_t stream) {
    const float* hs    = (const float*)d_in[0];
    const float* mask  = (const float*)d_in[1];
    const float* gw    = (const float*)d_in[2];
    const float* w1    = (const float*)d_in[3];
    const float* b1    = (const float*)d_in[4];
    const float* w2    = (const float*)d_in[5];
    const float* b2    = (const float*)d_in[6];
    const float* gamma = (const float*)d_in[7];
    const float* beta  = (const float*)d_in[8];
    float* out = (float*)d_out;

    char* ws = (char*)d_ws;
    int*   counts   = (int*)(ws + 0);
    int*   cursors  = (int*)(ws + 64);
    int*   offs     = (int*)(ws + 128);
    int*   ntiles   = (int*)(ws + 256);
    int*   tile_e   = (int*)(ws + 512);
    int*   tile_m   = (int*)(ws + 1024);
    int*   sel      = (int*)(ws + 4096);
    float* wgt      = (float*)(ws + 4096 + 1 * 32768);
    int*   slot_of  = (int*)(ws + 4096 + 2 * 32768);
    int*   tok_list = (int*)(ws + 4096 + 3 * 32768);
    float* tok_w    = (float*)(ws + 4096 + 4 * 32768);
    unsigned short* Hbf = (unsigned short*)(ws + (1ull << 20));    //  8 MiB
    unsigned short* W1t = (unsigned short*)(ws + (9ull << 20));    // 64 MiB  (E,I,D) bf16
    unsigned short* W2t = (unsigned short*)(ws + (73ull << 20));   // 64 MiB  (E,D,I) bf16
    unsigned short* mid = (unsigned short*)(ws + (137ull << 20));  // 64 MiB  (2T,I) bf16
    float* slotbuf      = (float*)(ws + (201ull << 20));           // 32 MiB  (2T,D) f32

    hipMemsetAsync(counts, 0, 64, stream);
    gate_kernel<<<T_TOK, 256, 0, stream>>>(hs, gw, counts, sel, wgt);
    offsets_kernel<<<1, 64, 0, stream>>>(counts, offs, cursors, out + (size_t)T_TOK * D_DIM,
                                         tile_e, tile_m, ntiles);
    scatter_kernel<<<T_TOK / 256, 256, 0, stream>>>(sel, wgt, offs, cursors, tok_list, tok_w, slot_of);
    cvtH_kernel<<<(T_TOK * D_DIM / 8) / 256, 256, 0, stream>>>(hs, Hbf);
    transpose_cvt_kernel<<<dim3(I_DIM / 32, D_DIM / 32, E_EXP), dim3(32, 8), 0, stream>>>(w1, W1t, D_DIM, I_DIM);
    transpose_cvt_kernel<<<dim3(D_DIM / 32, I_DIM / 32, E_EXP), dim3(32, 8), 0, stream>>>(w2, W2t, I_DIM, D_DIM);
    moe_gemm_kernel<0><<<dim3(MAX_TILES, I_DIM / 256), 512, 0, stream>>>(
        Hbf, W1t, b1, counts, offs, tile_e, tile_m, ntiles, tok_list, tok_w, mid, nullptr);
    moe_gemm_kernel<1><<<dim3(MAX_TILES, D_DIM / 128), 512, 0, stream>>>(
        mid, W2t, b2, counts, offs, tile_e, tile_m, ntiles, tok_list, tok_w, nullptr, slotbuf);
    ln_kernel<<<T_TOK, 256, 0, stream>>>(hs, mask, slotbuf, slot_of, gamma, beta, out);
}

// Round 2
// 777.213 us; speedup vs baseline: 1.0517x; 1.0517x over previous
//
#include <hip/hip_runtime.h>
#include <hip/hip_bf16.h>
#include <math.h>

#define T_TOK 4096
#define D_DIM 1024
#define I_DIM 4096
#define E_EXP 8
#define MAX_TILES 40

typedef __attribute__((ext_vector_type(8))) short bf16x8;
typedef __attribute__((ext_vector_type(4))) float f32x4;

__device__ __forceinline__ unsigned short f2bf(float x) {
    unsigned int u = __float_as_uint(x);
    u += 0x7fffu + ((u >> 16) & 1u);   // RNE
    return (unsigned short)(u >> 16);
}

// async global->LDS, 16B per lane; lds dest = wave-uniform base + lane*16
__device__ __forceinline__ void glds16(const unsigned short* g, unsigned short* l) {
    __builtin_amdgcn_global_load_lds(
        (const __attribute__((address_space(1))) unsigned int*)g,
        (__attribute__((address_space(3))) unsigned int*)(unsigned int)(unsigned long long)(void*)l,
        16, 0, 0);
}

#define VMWAIT4 asm volatile("s_waitcnt vmcnt(4)" ::: "memory")
#define VMWAIT0 asm volatile("s_waitcnt vmcnt(0)" ::: "memory")
#define LGKM0   asm volatile("s_waitcnt lgkmcnt(0)" ::: "memory")

__device__ __forceinline__ void bar() {
    __builtin_amdgcn_s_barrier();
}

// ---------------- gate: logits (fp32 exact), softmax, top-2, weights ----------------
__global__ void gate_kernel(const float* __restrict__ h, const float* __restrict__ gw,
                            int* __restrict__ counts, int* __restrict__ sel,
                            float* __restrict__ wgt) {
    int t = blockIdx.x;
    int tid = threadIdx.x;
    float acc[E_EXP];
#pragma unroll
    for (int e = 0; e < E_EXP; e++) acc[e] = 0.f;
    const float* hr = h + (size_t)t * D_DIM;
    for (int d = tid; d < D_DIM; d += 256) {
        float hv = hr[d];
#pragma unroll
        for (int e = 0; e < E_EXP; e++) acc[e] += hv * gw[e * D_DIM + d];
    }
#pragma unroll
    for (int e = 0; e < E_EXP; e++)
        for (int off = 32; off > 0; off >>= 1) acc[e] += __shfl_down(acc[e], off, 64);
    __shared__ float red[4][E_EXP];
    int wave = tid >> 6, lane = tid & 63;
    if (lane == 0) {
#pragma unroll
        for (int e = 0; e < E_EXP; e++) red[wave][e] = acc[e];
    }
    __syncthreads();
    if (tid == 0) {
        float lg[E_EXP];
#pragma unroll
        for (int e = 0; e < E_EXP; e++) lg[e] = red[0][e] + red[1][e] + red[2][e] + red[3][e];
        float mx = lg[0];
#pragma unroll
        for (int e = 1; e < E_EXP; e++) mx = fmaxf(mx, lg[e]);
        float p[E_EXP];
#pragma unroll
        for (int e = 0; e < E_EXP; e++) p[e] = expf(lg[e] - mx);
        int i0 = 0; float b0 = p[0];
#pragma unroll
        for (int e = 1; e < E_EXP; e++) if (p[e] > b0) { b0 = p[e]; i0 = e; }
        int i1 = -1; float b1v = -1.f;
#pragma unroll
        for (int e = 0; e < E_EXP; e++) if (e != i0 && p[e] > b1v) { b1v = p[e]; i1 = e; }
        float den = b0 + b1v;
        sel[2 * t] = i0; sel[2 * t + 1] = i1;
        wgt[2 * t] = b0 / den; wgt[2 * t + 1] = b1v / den;
        atomicAdd(&counts[i0], 1);
        atomicAdd(&counts[i1], 1);
    }
}

// ---------------- offsets + cursors + aux loss + compacted tile table (BM=256) ----------------
__global__ void offsets_kernel(const int* __restrict__ counts, int* __restrict__ offs,
                               int* __restrict__ cursors, float* __restrict__ aux_out,
                               int* __restrict__ tile_e, int* __restrict__ tile_m,
                               int* __restrict__ ntiles) {
    if (blockIdx.x == 0 && threadIdx.x == 0) {
        int off = 0; float aux = 0.f; int nt = 0;
        for (int e = 0; e < E_EXP; e++) {
            offs[e] = off; off += counts[e]; cursors[e] = 0;
            float u = (float)counts[e] / (float)T_TOK;
            float d = u - 1.0f / (float)E_EXP;
            aux += d * d;
            for (int m0 = 0; m0 < counts[e]; m0 += 256) {
                tile_e[nt] = e; tile_m[nt] = m0; nt++;
            }
        }
        ntiles[0] = nt;
        aux_out[0] = aux / (float)E_EXP;
    }
}

// ---------------- scatter tokens into per-expert segments ----------------
__global__ void scatter_kernel(const int* __restrict__ sel, const float* __restrict__ wgt,
                               const int* __restrict__ offs, int* __restrict__ cursors,
                               int* __restrict__ tok_list, float* __restrict__ tok_w,
                               int* __restrict__ slot_of) {
    int t = blockIdx.x * 256 + threadIdx.x;
    if (t >= T_TOK) return;
#pragma unroll
    for (int k = 0; k < 2; k++) {
        int e = sel[2 * t + k];
        int pos = atomicAdd(&cursors[e], 1);
        int idx = offs[e] + pos;
        tok_list[idx] = t;
        tok_w[idx] = wgt[2 * t + k];
        slot_of[2 * t + k] = idx;
    }
}

// ---------------- H fp32 -> bf16 ----------------
__global__ void cvtH_kernel(const float* __restrict__ src, unsigned short* __restrict__ dst) {
    size_t i = ((size_t)blockIdx.x * 256 + threadIdx.x) * 8;
    float4 a = *(const float4*)(src + i);
    float4 b = *(const float4*)(src + i + 4);
    union { unsigned short u[8]; uint4 v; } o;
    o.u[0] = f2bf(a.x); o.u[1] = f2bf(a.y); o.u[2] = f2bf(a.z); o.u[3] = f2bf(a.w);
    o.u[4] = f2bf(b.x); o.u[5] = f2bf(b.y); o.u[6] = f2bf(b.z); o.u[7] = f2bf(b.w);
    *(uint4*)(dst + i) = o.v;
}

// ---------------- weight transpose + fp32->bf16: (E,R,C) -> (E,C,R) ----------------
__global__ void transpose_cvt_kernel(const float* __restrict__ src, unsigned short* __restrict__ dst,
                                     int R, int C) {
    __shared__ float tile[32][33];
    int e = blockIdx.z;
    const float* s = src + (size_t)e * R * C;
    unsigned short* d = dst + (size_t)e * R * C;
    int c0 = blockIdx.x * 32, r0 = blockIdx.y * 32;
    int tx = threadIdx.x, ty = threadIdx.y;
#pragma unroll
    for (int j = 0; j < 4; j++)
        tile[ty + 8 * j][tx] = s[(size_t)(r0 + ty + 8 * j) * C + c0 + tx];
    __syncthreads();
#pragma unroll
    for (int j = 0; j < 4; j++)
        d[(size_t)(c0 + ty + 8 * j) * R + r0 + tx] = f2bf(tile[tx][ty + 8 * j]);
}

// ---------------- grouped GEMM, 256x256 tile, 8 waves, 8-phase schedule (m201 port) --------
// Fine interleave: per phase {ds_read subtile || 2 glds -> bar -> lgkm0 -> 16 MFMA -> bar},
// counted vmcnt(4) twice per 2-K-tile iteration, never 0 in steady state.
// LDS read swizzle: phys 16B-slot = slot ^ ((row>>1)&3); glds source column pre-swizzled so
// LDS dest stays linear (both-sides-or-neither rule).
// MODE 0: mid = gelu(gather(Hbf) @ W1t^T + b1)   -> bf16 mid (2T x I)
// MODE 1: slotbuf = tok_w * (mid @ W2t^T + b2)   -> fp32 slotbuf (2T x D)
template <int MODE>
__launch_bounds__(512, 2)
__global__ void moe_gemm_kernel(const unsigned short* __restrict__ Abase,
                                const unsigned short* __restrict__ Bt,
                                const float* __restrict__ bias,
                                const int* __restrict__ counts, const int* __restrict__ offs,
                                const int* __restrict__ tile_e, const int* __restrict__ tile_m,
                                const int* __restrict__ ntiles,
                                const int* __restrict__ tok_list, const float* __restrict__ tok_w,
                                unsigned short* __restrict__ midout, float* __restrict__ slotbuf) {
    constexpr int K  = (MODE == 0) ? D_DIM : I_DIM;
    constexpr int N  = (MODE == 0) ? I_DIM : D_DIM;
    constexpr int NT = K / 32;     // K-tiles of BK=32

    // 4-deep ring: computing tiles kt,kt+1 while tiles kt+2,kt+3 land/stage
    __shared__ __align__(16) unsigned short lA[4][256 * 32];
    __shared__ __align__(16) unsigned short lB[4][256 * 32];

    // bijective XCD chunk remap: consecutive work-ids (same A panel / expert) stay on one XCD
    const int nwg  = gridDim.x * gridDim.y;
    const int flat = blockIdx.y * gridDim.x + blockIdx.x;
    const int q8 = nwg >> 3, r8 = nwg & 7;
    const int xcd = flat & 7, pos = flat >> 3;
    const int id2 = (xcd < r8 ? xcd * (q8 + 1) : r8 * (q8 + 1) + (xcd - r8) * q8) + pos;
    const int tix = id2 / gridDim.y;
    const int nb  = id2 % gridDim.y;
    if (tix >= ntiles[0]) return;

    const int e   = tile_e[tix];
    const int m0  = tile_m[tix];
    const int Ne  = counts[e];
    const int seg = offs[e];
    const int n0  = nb * 256;

    const int tid  = threadIdx.x;
    const int w    = tid >> 6;
    const int lane = tid & 63;
    const int quad = lane >> 4;
    const int l15  = lane & 15;
    const int wm   = (w >> 2) * 128;   // wave row offset (2 row-halves of 64 each)
    const int wn   = (w & 3) * 64;     // wave col offset

    // staging: each glds call covers 16 rows x 64B; lane l -> row base+(l>>2), phys slot l&3.
    // pre-swizzled source column: logical slot = (l&3) ^ g(row), g(row)=(row>>1)&3=(l>>3)&3
    const int lrow = lane >> 2;
    const int scol = (((lane & 3) ^ ((lane >> 3) & 3)) & 3) * 8;   // shorts
    // read swizzle: phys slot = quad ^ ((row>>1)&3), row bits[2:1] == l15 bits[2:1]
    const int rs   = (((quad ^ ((l15 >> 1) & 3)) & 3) * 8);        // shorts

    const unsigned short *gA0, *gA1;
    {
        int mr0 = m0 + w * 32 + lrow;
        int mr1 = mr0 + 16;
        int c0 = (mr0 < Ne) ? mr0 : 0;
        int c1 = (mr1 < Ne) ? mr1 : 0;
        size_t r0, r1;
        if (MODE == 0) { r0 = (size_t)tok_list[seg + c0] * K; r1 = (size_t)tok_list[seg + c1] * K; }
        else           { r0 = (size_t)(seg + c0) * K;         r1 = (size_t)(seg + c1) * K; }
        gA0 = Abase + r0 + scol;
        gA1 = Abase + r1 + scol;
    }
    const unsigned short* Bte = Bt + (size_t)e * N * K;
    const unsigned short* gB0 = Bte + (size_t)(n0 + w * 32 + lrow) * K + scol;
    const unsigned short* gB1 = gB0 + (size_t)16 * K;

    auto ISSUE_A = [&](int t) {
        const int b = t & 3, off = t * 32;
        glds16(gA0 + off, &lA[b][w * 1024]);
        glds16(gA1 + off, &lA[b][w * 1024 + 512]);
    };
    auto ISSUE_B = [&](int t) {
        const int b = t & 3, off = t * 32;
        glds16(gB0 + off, &lB[b][w * 1024]);
        glds16(gB1 + off, &lB[b][w * 1024 + 512]);
    };

    f32x4 acc[8][4];
#pragma unroll
    for (int a = 0; a < 8; a++)
#pragma unroll
        for (int j = 0; j < 4; j++) acc[a][j] = (f32x4){0.f, 0.f, 0.f, 0.f};

    bf16x8 bv[4], av[4];
    auto READ_BV = [&](int t) {
        const unsigned short* LB = lB[t & 3];
#pragma unroll
        for (int j = 0; j < 4; j++)
            bv[j] = *(const bf16x8*)&LB[(wn + j * 16 + l15) * 32 + rs];
    };
    auto READ_AV = [&](int t, int pm) {
        const unsigned short* LA = lA[t & 3];
#pragma unroll
        for (int ii = 0; ii < 4; ii++)
            av[ii] = *(const bf16x8*)&LA[(wm + pm * 64 + ii * 16 + l15) * 32 + rs];
    };
    auto MFMA16 = [&](int pm) {
        __builtin_amdgcn_s_setprio(1);
#pragma unroll
        for (int ii = 0; ii < 4; ii++)
#pragma unroll
            for (int j = 0; j < 4; j++)
                acc[pm * 4 + ii][j] = __builtin_amdgcn_mfma_f32_16x16x32_bf16(
                    av[ii], bv[j], acc[pm * 4 + ii][j], 0, 0, 0);
        __builtin_amdgcn_s_setprio(0);
    };

    // prologue: stage tiles 0,1; wait tile 0 landed (tile 1 stays in flight)
    ISSUE_A(0); ISSUE_B(0);
    ISSUE_A(1); ISSUE_B(1);
    VMWAIT4;
    bar();

    for (int kt = 0; kt < NT - 2; kt += 2) {
        // P0: tile kt row-half 0
        READ_BV(kt); READ_AV(kt, 0);
        ISSUE_A(kt + 2);
        bar(); LGKM0; MFMA16(0); bar();
        // P1: tile kt row-half 1; ensure tile kt+1 landed before P2 reads it
        READ_AV(kt, 1);
        ISSUE_B(kt + 2);
        VMWAIT4;                    // oldest 4 (= tile kt+1) done; tile kt+2 in flight
        bar(); LGKM0; MFMA16(1); bar();
        // P2: tile kt+1 row-half 0
        READ_BV(kt + 1); READ_AV(kt + 1, 0);
        ISSUE_A(kt + 3);
        bar(); LGKM0; MFMA16(0); bar();
        // P3: tile kt+1 row-half 1; ensure tile kt+2 landed
        READ_AV(kt + 1, 1);
        ISSUE_B(kt + 3);
        VMWAIT4;                    // oldest 4 (= tile kt+2) done; tile kt+3 in flight
        bar(); LGKM0; MFMA16(1); bar();
    }
    {   // tail: kt = NT-2 (no staging left)
        READ_BV(NT - 2); READ_AV(NT - 2, 0);
        bar(); LGKM0; MFMA16(0); bar();
        READ_AV(NT - 2, 1);
        VMWAIT0;                    // tile NT-1 landed
        bar(); LGKM0; MFMA16(1); bar();
        READ_BV(NT - 1); READ_AV(NT - 1, 0);
        bar(); LGKM0; MFMA16(0); bar();
        READ_AV(NT - 1, 1);
        LGKM0; MFMA16(1);
    }

    // ---- epilogue ----
    const float* be = bias + (size_t)e * N;
#pragma unroll
    for (int a = 0; a < 8; a++) {
        const int mbase = m0 + wm + (a >> 2) * 64 + (a & 3) * 16 + quad * 4;
#pragma unroll
        for (int j = 0; j < 4; j++) {
            const int n = n0 + wn + j * 16 + l15;
            const float bvl = be[n];
#pragma unroll
            for (int r = 0; r < 4; r++) {
                const int m = mbase + r;
                if (m < Ne) {
                    float v = acc[a][j][r] + bvl;
                    if (MODE == 0) {
                        v = 0.5f * v * (1.0f + erff(v * 0.70710678118654752f));
                        midout[(size_t)(seg + m) * N + n] = f2bf(v);
                    } else {
                        slotbuf[(size_t)(seg + m) * N + n] = tok_w[seg + m] * v;
                    }
                }
            }
        }
    }
}

// ---------------- residual + mask + LayerNorm ----------------
__global__ void ln_kernel(const float* __restrict__ hs, const float* __restrict__ mask,
                          const float* __restrict__ slotbuf, const int* __restrict__ slot_of,
                          const float* __restrict__ gamma, const float* __restrict__ beta,
                          float* __restrict__ outp) {
    int t = blockIdx.x, tid = threadIdx.x;
    int s0 = slot_of[2 * t], s1 = slot_of[2 * t + 1];
    float mk = mask[t];
    const float4* hr = (const float4*)(hs + (size_t)t * D_DIM);
    const float4* p0 = (const float4*)(slotbuf + (size_t)s0 * D_DIM);
    const float4* p1 = (const float4*)(slotbuf + (size_t)s1 * D_DIM);
    float4 hv = hr[tid], a = p0[tid], b = p1[tid];
    float x0 = hv.x + mk * (a.x + b.x);
    float x1 = hv.y + mk * (a.y + b.y);
    float x2 = hv.z + mk * (a.z + b.z);
    float x3 = hv.w + mk * (a.w + b.w);
    float sum = x0 + x1 + x2 + x3;
    float sq = x0 * x0 + x1 * x1 + x2 * x2 + x3 * x3;
    for (int off = 32; off > 0; off >>= 1) {
        sum += __shfl_down(sum, off, 64);
        sq += __shfl_down(sq, off, 64);
    }
    __shared__ float rsum[4], rsq[4];
    __shared__ float mu_s, rstd_s;
    int wave = tid >> 6, lane = tid & 63;
    if (lane == 0) { rsum[wave] = sum; rsq[wave] = sq; }
    __syncthreads();
    if (tid == 0) {
        float s = rsum[0] + rsum[1] + rsum[2] + rsum[3];
        float q = rsq[0] + rsq[1] + rsq[2] + rsq[3];
        float mu = s / (float)D_DIM;
        float var = q / (float)D_DIM - mu * mu;
        mu_s = mu; rstd_s = rsqrtf(var + 1e-5f);
    }
    __syncthreads();
    float mu = mu_s, rstd = rstd_s;
    const float4* g4 = (const float4*)gamma;
    const float4* b4 = (const float4*)beta;
    float4 g = g4[tid], bb = b4[tid];
    float4 o;
    o.x = (x0 - mu) * rstd * g.x + bb.x;
    o.y = (x1 - mu) * rstd * g.y + bb.y;
    o.z = (x2 - mu) * rstd * g.z + bb.z;
    o.w = (x3 - mu) * rstd * g.w + bb.w;
    ((float4*)(outp + (size_t)t * D_DIM))[tid] = o;
}

extern "C" void kernel_launch(void* const* d_in, const int* in_sizes, int n_in,
                              void* d_out, int out_size, void* d_ws, size_t ws_size,
                              hipStream_t stream) {
    const float* hs    = (const float*)d_in[0];
    const float* mask  = (const float*)d_in[1];
    const float* gw    = (const float*)d_in[2];
    const float* w1    = (const float*)d_in[3];
    const float* b1    = (const float*)d_in[4];
    const float* w2    = (const float*)d_in[5];
    const float* b2    = (const float*)d_in[6];
    const float* gamma = (const float*)d_in[7];
    const float* beta  = (const float*)d_in[8];
    float* out = (float*)d_out;

    char* ws = (char*)d_ws;
    int*   counts   = (int*)(ws + 0);
    int*   cursors  = (int*)(ws + 64);
    int*   offs     = (int*)(ws + 128);
    int*   ntiles   = (int*)(ws + 256);
    int*   tile_e   = (int*)(ws + 512);
    int*   tile_m   = (int*)(ws + 1024);
    int*   sel      = (int*)(ws + 4096);
    float* wgt      = (float*)(ws + 4096 + 1 * 32768);
    int*   slot_of  = (int*)(ws + 4096 + 2 * 32768);
    int*   tok_list = (int*)(ws + 4096 + 3 * 32768);
    float* tok_w    = (float*)(ws + 4096 + 4 * 32768);
    unsigned short* Hbf = (unsigned short*)(ws + (1ull << 20));    //  8 MiB
    unsigned short* W1t = (unsigned short*)(ws + (9ull << 20));    // 64 MiB  (E,I,D) bf16
    unsigned short* W2t = (unsigned short*)(ws + (73ull << 20));   // 64 MiB  (E,D,I) bf16
    unsigned short* mid = (unsigned short*)(ws + (137ull << 20));  // 64 MiB  (2T,I) bf16
    float* slotbuf      = (float*)(ws + (201ull << 20));           // 32 MiB  (2T,D) f32

    hipMemsetAsync(counts, 0, 64, stream);
    gate_kernel<<<T_TOK, 256, 0, stream>>>(hs, gw, counts, sel, wgt);
    offsets_kernel<<<1, 64, 0, stream>>>(counts, offs, cursors, out + (size_t)T_TOK * D_DIM,
                                         tile_e, tile_m, ntiles);
    scatter_kernel<<<T_TOK / 256, 256, 0, stream>>>(sel, wgt, offs, cursors, tok_list, tok_w, slot_of);
    cvtH_kernel<<<(T_TOK * D_DIM / 8) / 256, 256, 0, stream>>>(hs, Hbf);
    transpose_cvt_kernel<<<dim3(I_DIM / 32, D_DIM / 32, E_EXP), dim3(32, 8), 0, stream>>>(w1, W1t, D_DIM, I_DIM);
    transpose_cvt_kernel<<<dim3(D_DIM / 32, I_DIM / 32, E_EXP), dim3(32, 8), 0, stream>>>(w2, W2t, I_DIM, D_DIM);
    moe_gemm_kernel<0><<<dim3(MAX_TILES, I_DIM / 256), 512, 0, stream>>>(
        Hbf, W1t, b1, counts, offs, tile_e, tile_m, ntiles, tok_list, tok_w, mid, nullptr);
    moe_gemm_kernel<1><<<dim3(MAX_TILES, D_DIM / 256), 512, 0, stream>>>(
        mid, W2t, b2, counts, offs, tile_e, tile_m, ntiles, tok_list, tok_w, nullptr, slotbuf);
    ln_kernel<<<T_TOK, 256, 0, stream>>>(hs, mask, slotbuf, slot_of, gamma, beta, out);
}

// Round 4
// 734.606 us; speedup vs baseline: 1.1127x; 1.0580x over previous
//
#include <hip/hip_runtime.h>
#include <hip/hip_bf16.h>
#include <math.h>

#define T_TOK 4096
#define D_DIM 1024
#define I_DIM 4096
#define E_EXP 8
#define MAX_TILES 72

typedef __attribute__((ext_vector_type(8))) short bf16x8;
typedef __attribute__((ext_vector_type(4))) float f32x4;

__device__ __forceinline__ unsigned short f2bf(float x) {
    unsigned int u = __float_as_uint(x);
    u += 0x7fffu + ((u >> 16) & 1u);   // RNE
    return (unsigned short)(u >> 16);
}

// async global->LDS, 16B per lane; lds dest = wave-uniform base + lane*16
__device__ __forceinline__ void glds16(const unsigned short* g, unsigned short* l) {
    __builtin_amdgcn_global_load_lds(
        (const __attribute__((address_space(1))) unsigned int*)g,
        (__attribute__((address_space(3))) unsigned int*)(unsigned int)(unsigned long long)(void*)l,
        16, 0, 0);
}

#define VMWAIT4 asm volatile("s_waitcnt vmcnt(4)" ::: "memory")
#define VMWAIT0 asm volatile("s_waitcnt vmcnt(0)" ::: "memory")

__device__ __forceinline__ void bar() {
    asm volatile("" ::: "memory");
    __builtin_amdgcn_s_barrier();
    asm volatile("" ::: "memory");
}

// ---------------- gate: logits (fp32 exact), softmax, top-2, weights ----------------
__global__ void gate_kernel(const float* __restrict__ h, const float* __restrict__ gw,
                            int* __restrict__ counts, int* __restrict__ sel,
                            float* __restrict__ wgt) {
    int t = blockIdx.x;
    int tid = threadIdx.x;
    float acc[E_EXP];
#pragma unroll
    for (int e = 0; e < E_EXP; e++) acc[e] = 0.f;
    const float* hr = h + (size_t)t * D_DIM;
    for (int d = tid; d < D_DIM; d += 256) {
        float hv = hr[d];
#pragma unroll
        for (int e = 0; e < E_EXP; e++) acc[e] += hv * gw[e * D_DIM + d];
    }
#pragma unroll
    for (int e = 0; e < E_EXP; e++)
        for (int off = 32; off > 0; off >>= 1) acc[e] += __shfl_down(acc[e], off, 64);
    __shared__ float red[4][E_EXP];
    int wave = tid >> 6, lane = tid & 63;
    if (lane == 0) {
#pragma unroll
        for (int e = 0; e < E_EXP; e++) red[wave][e] = acc[e];
    }
    __syncthreads();
    if (tid == 0) {
        float lg[E_EXP];
#pragma unroll
        for (int e = 0; e < E_EXP; e++) lg[e] = red[0][e] + red[1][e] + red[2][e] + red[3][e];
        float mx = lg[0];
#pragma unroll
        for (int e = 1; e < E_EXP; e++) mx = fmaxf(mx, lg[e]);
        float p[E_EXP];
#pragma unroll
        for (int e = 0; e < E_EXP; e++) p[e] = expf(lg[e] - mx);
        int i0 = 0; float b0 = p[0];
#pragma unroll
        for (int e = 1; e < E_EXP; e++) if (p[e] > b0) { b0 = p[e]; i0 = e; }
        int i1 = -1; float b1v = -1.f;
#pragma unroll
        for (int e = 0; e < E_EXP; e++) if (e != i0 && p[e] > b1v) { b1v = p[e]; i1 = e; }
        float den = b0 + b1v;
        sel[2 * t] = i0; sel[2 * t + 1] = i1;
        wgt[2 * t] = b0 / den; wgt[2 * t + 1] = b1v / den;
        atomicAdd(&counts[i0], 1);
        atomicAdd(&counts[i1], 1);
    }
}

// ---------------- offsets + cursors + aux loss + compacted tile table (BM=128) ----------------
__global__ void offsets_kernel(const int* __restrict__ counts, int* __restrict__ offs,
                               int* __restrict__ cursors, float* __restrict__ aux_out,
                               int* __restrict__ tile_e, int* __restrict__ tile_m,
                               int* __restrict__ ntiles) {
    if (blockIdx.x == 0 && threadIdx.x == 0) {
        int off = 0; float aux = 0.f; int nt = 0;
        for (int e = 0; e < E_EXP; e++) {
            offs[e] = off; off += counts[e]; cursors[e] = 0;
            float u = (float)counts[e] / (float)T_TOK;
            float d = u - 1.0f / (float)E_EXP;
            aux += d * d;
            for (int m0 = 0; m0 < counts[e]; m0 += 128) {
                tile_e[nt] = e; tile_m[nt] = m0; nt++;
            }
        }
        ntiles[0] = nt;
        aux_out[0] = aux / (float)E_EXP;
    }
}

// ---------------- scatter tokens into per-expert segments ----------------
__global__ void scatter_kernel(const int* __restrict__ sel, const float* __restrict__ wgt,
                               const int* __restrict__ offs, int* __restrict__ cursors,
                               int* __restrict__ tok_list, float* __restrict__ tok_w,
                               int* __restrict__ slot_of) {
    int t = blockIdx.x * 256 + threadIdx.x;
    if (t >= T_TOK) return;
#pragma unroll
    for (int k = 0; k < 2; k++) {
        int e = sel[2 * t + k];
        int pos = atomicAdd(&cursors[e], 1);
        int idx = offs[e] + pos;
        tok_list[idx] = t;
        tok_w[idx] = wgt[2 * t + k];
        slot_of[2 * t + k] = idx;
    }
}

// ---------------- H fp32 -> bf16 ----------------
__global__ void cvtH_kernel(const float* __restrict__ src, unsigned short* __restrict__ dst) {
    size_t i = ((size_t)blockIdx.x * 256 + threadIdx.x) * 8;
    float4 a = *(const float4*)(src + i);
    float4 b = *(const float4*)(src + i + 4);
    union { unsigned short u[8]; uint4 v; } o;
    o.u[0] = f2bf(a.x); o.u[1] = f2bf(a.y); o.u[2] = f2bf(a.z); o.u[3] = f2bf(a.w);
    o.u[4] = f2bf(b.x); o.u[5] = f2bf(b.y); o.u[6] = f2bf(b.z); o.u[7] = f2bf(b.w);
    *(uint4*)(dst + i) = o.v;
}

// ---------------- weight transpose + fp32->bf16: (E,R,C) -> (E,C,R) ----------------
__global__ void transpose_cvt_kernel(const float* __restrict__ src, unsigned short* __restrict__ dst,
                                     int R, int C) {
    __shared__ float tile[32][33];
    int e = blockIdx.z;
    const float* s = src + (size_t)e * R * C;
    unsigned short* d = dst + (size_t)e * R * C;
    int c0 = blockIdx.x * 32, r0 = blockIdx.y * 32;
    int tx = threadIdx.x, ty = threadIdx.y;
#pragma unroll
    for (int j = 0; j < 4; j++)
        tile[ty + 8 * j][tx] = s[(size_t)(r0 + ty + 8 * j) * C + c0 + tx];
    __syncthreads();
#pragma unroll
    for (int j = 0; j < 4; j++)
        d[(size_t)(c0 + ty + 8 * j) * R + r0 + tx] = f2bf(tile[tx][ty + 8 * j]);
}

// ---------------- grouped GEMM, 128x128 tile, 4 waves, 2-deep ring + counted vmcnt ----------
// m97-structure (multi-block/CU for cross-block overlap) + zero-conflict XOR swizzle (r2,
// measured 0 conflicts) + issue-early staging: STAGE(kt+1); vmcnt(4); bar; compute(kt); bar.
// Next tile's 4 glds stay in flight across the whole compute phase; drain only at the end.
// __launch_bounds__(256,4): cap 128 VGPR -> guarantee 4 blocks/CU for cross-block overlap.
// MODE 0: mid = gelu(gather(Hbf) @ W1t^T + b1)   -> bf16 mid (2T x I)
// MODE 1: slotbuf = tok_w * (mid @ W2t^T + b2)   -> fp32 slotbuf (2T x D)
template <int MODE>
__launch_bounds__(256, 4)
__global__ void moe_gemm_kernel(const unsigned short* __restrict__ Abase,
                                const unsigned short* __restrict__ Bt,
                                const float* __restrict__ bias,
                                const int* __restrict__ counts, const int* __restrict__ offs,
                                const int* __restrict__ tile_e, const int* __restrict__ tile_m,
                                const int* __restrict__ ntiles,
                                const int* __restrict__ tok_list, const float* __restrict__ tok_w,
                                unsigned short* __restrict__ midout, float* __restrict__ slotbuf) {
    constexpr int K  = (MODE == 0) ? D_DIM : I_DIM;
    constexpr int N  = (MODE == 0) ? I_DIM : D_DIM;
    constexpr int NT = K / 32;     // K-tiles of BK=32

    // 2-deep ring: 2 x (128 rows x 32 shorts) for A and B = 32 KiB total
    __shared__ __align__(16) unsigned short lA[2][128 * 32];
    __shared__ __align__(16) unsigned short lB[2][128 * 32];

    // bijective XCD chunk remap: consecutive work-ids share the A-panel/expert -> L2 locality
    const int nwg  = gridDim.x * gridDim.y;
    const int flat = blockIdx.y * gridDim.x + blockIdx.x;
    const int q8 = nwg >> 3, r8 = nwg & 7;
    const int xcd = flat & 7, pos = flat >> 3;
    const int id2 = (xcd < r8 ? xcd * (q8 + 1) : r8 * (q8 + 1) + (xcd - r8) * q8) + pos;
    const int tix = id2 / gridDim.y;
    const int nb  = id2 % gridDim.y;
    if (tix >= ntiles[0]) return;

    const int e   = tile_e[tix];
    const int m0  = tile_m[tix];
    const int Ne  = counts[e];
    const int seg = offs[e];
    const int n0  = nb * 128;

    const int tid  = threadIdx.x;
    const int w    = tid >> 6;
    const int lane = tid & 63;
    const int quad = lane >> 4;
    const int l15  = lane & 15;
    const int wm   = (w >> 1) * 64;    // wave row offset
    const int wn   = (w & 1) * 64;     // wave col offset

    // staging: each glds covers 16 rows x 64B; lane l -> row base+(l>>2), phys slot l&3.
    // pre-swizzled source column: logical slot = (l&3) ^ ((l>>3)&3)  [row bits 2:1]
    const int lrow = lane >> 2;
    const int scol = (((lane & 3) ^ ((lane >> 3) & 3)) & 3) * 8;   // shorts
    // read swizzle: phys slot = quad ^ (row bits 2:1) = quad ^ ((l15>>1)&3)
    const int rs   = (((quad ^ ((l15 >> 1) & 3)) & 3) * 8);        // shorts

    const unsigned short *gA0, *gA1;
    {
        int mr0 = m0 + w * 32 + lrow;
        int mr1 = mr0 + 16;
        int c0 = (mr0 < Ne) ? mr0 : 0;
        int c1 = (mr1 < Ne) ? mr1 : 0;
        size_t r0, r1;
        if (MODE == 0) { r0 = (size_t)tok_list[seg + c0] * K; r1 = (size_t)tok_list[seg + c1] * K; }
        else           { r0 = (size_t)(seg + c0) * K;         r1 = (size_t)(seg + c1) * K; }
        gA0 = Abase + r0 + scol;
        gA1 = Abase + r1 + scol;
    }
    const unsigned short* Bte = Bt + (size_t)e * N * K;
    const unsigned short* gB0 = Bte + (size_t)(n0 + w * 32 + lrow) * K + scol;
    const unsigned short* gB1 = gB0 + (size_t)16 * K;

    auto STAGE = [&](int t) {
        const int b = t & 1, off = t * 32;
        glds16(gA0 + off, &lA[b][(w * 32) * 32]);
        glds16(gA1 + off, &lA[b][(w * 32 + 16) * 32]);
        glds16(gB0 + off, &lB[b][(w * 32) * 32]);
        glds16(gB1 + off, &lB[b][(w * 32 + 16) * 32]);
    };

    f32x4 acc[4][4];
#pragma unroll
    for (int i = 0; i < 4; i++)
#pragma unroll
        for (int j = 0; j < 4; j++) acc[i][j] = (f32x4){0.f, 0.f, 0.f, 0.f};

    STAGE(0);
    for (int kt = 0; kt < NT; ++kt) {
        if (kt + 1 < NT) {
            STAGE(kt + 1);     // issue next tile FIRST: stays in flight across compute
            VMWAIT4;           // oldest 4 (= tile kt) landed; next 4 remain outstanding
        } else {
            VMWAIT0;           // final tile: full drain
        }
        bar();
        const unsigned short* LA = lA[kt & 1];
        const unsigned short* LB = lB[kt & 1];
        bf16x8 av[4], bv[4];
#pragma unroll
        for (int i = 0; i < 4; i++)
            av[i] = *(const bf16x8*)&LA[(wm + i * 16 + l15) * 32 + rs];
#pragma unroll
        for (int j = 0; j < 4; j++)
            bv[j] = *(const bf16x8*)&LB[(wn + j * 16 + l15) * 32 + rs];
        __builtin_amdgcn_s_setprio(1);
#pragma unroll
        for (int i = 0; i < 4; i++)
#pragma unroll
            for (int j = 0; j < 4; j++)
                acc[i][j] = __builtin_amdgcn_mfma_f32_16x16x32_bf16(av[i], bv[j], acc[i][j], 0, 0, 0);
        __builtin_amdgcn_s_setprio(0);
        bar();                 // readers done before next iter's STAGE overwrites the other buffer
    }

    // ---- epilogue ----
    const float* be = bias + (size_t)e * N;
#pragma unroll
    for (int i = 0; i < 4; i++) {
        const int mbase = m0 + wm + i * 16 + quad * 4;
#pragma unroll
        for (int j = 0; j < 4; j++) {
            const int n = n0 + wn + j * 16 + l15;
            const float bvl = be[n];
#pragma unroll
            for (int r = 0; r < 4; r++) {
                const int m = mbase + r;
                if (m < Ne) {
                    float v = acc[i][j][r] + bvl;
                    if (MODE == 0) {
                        v = 0.5f * v * (1.0f + erff(v * 0.70710678118654752f));
                        midout[(size_t)(seg + m) * N + n] = f2bf(v);
                    } else {
                        slotbuf[(size_t)(seg + m) * N + n] = tok_w[seg + m] * v;
                    }
                }
            }
        }
    }
}

// ---------------- residual + mask + LayerNorm ----------------
__global__ void ln_kernel(const float* __restrict__ hs, const float* __restrict__ mask,
                          const float* __restrict__ slotbuf, const int* __restrict__ slot_of,
                          const float* __restrict__ gamma, const float* __restrict__ beta,
                          float* __restrict__ outp) {
    int t = blockIdx.x, tid = threadIdx.x;
    int s0 = slot_of[2 * t], s1 = slot_of[2 * t + 1];
    float mk = mask[t];
    const float4* hr = (const float4*)(hs + (size_t)t * D_DIM);
    const float4* p0 = (const float4*)(slotbuf + (size_t)s0 * D_DIM);
    const float4* p1 = (const float4*)(slotbuf + (size_t)s1 * D_DIM);
    float4 hv = hr[tid], a = p0[tid], b = p1[tid];
    float x0 = hv.x + mk * (a.x + b.x);
    float x1 = hv.y + mk * (a.y + b.y);
    float x2 = hv.z + mk * (a.z + b.z);
    float x3 = hv.w + mk * (a.w + b.w);
    float sum = x0 + x1 + x2 + x3;
    float sq = x0 * x0 + x1 * x1 + x2 * x2 + x3 * x3;
    for (int off = 32; off > 0; off >>= 1) {
        sum += __shfl_down(sum, off, 64);
        sq += __shfl_down(sq, off, 64);
    }
    __shared__ float rsum[4], rsq[4];
    __shared__ float mu_s, rstd_s;
    int wave = tid >> 6, lane = tid & 63;
    if (lane == 0) { rsum[wave] = sum; rsq[wave] = sq; }
    __syncthreads();
    if (tid == 0) {
        float s = rsum[0] + rsum[1] + rsum[2] + rsum[3];
        float q = rsq[0] + rsq[1] + rsq[2] + rsq[3];
        float mu = s / (float)D_DIM;
        float var = q / (float)D_DIM - mu * mu;
        mu_s = mu; rstd_s = rsqrtf(var + 1e-5f);
    }
    __syncthreads();
    float mu = mu_s, rstd = rstd_s;
    const float4* g4 = (const float4*)gamma;
    const float4* b4 = (const float4*)beta;
    float4 g = g4[tid], bb = b4[tid];
    float4 o;
    o.x = (x0 - mu) * rstd * g.x + bb.x;
    o.y = (x1 - mu) * rstd * g.y + bb.y;
    o.z = (x2 - mu) * rstd * g.z + bb.z;
    o.w = (x3 - mu) * rstd * g.w + bb.w;
    ((float4*)(outp + (size_t)t * D_DIM))[tid] = o;
}

extern "C" void kernel_launch(void* const* d_in, const int* in_sizes, int n_in,
                              void* d_out, int out_size, void* d_ws, size_t ws_size,
                              hipStream_t stream) {
    const float* hs    = (const float*)d_in[0];
    const float* mask  = (const float*)d_in[1];
    const float* gw    = (const float*)d_in[2];
    const float* w1    = (const float*)d_in[3];
    const float* b1    = (const float*)d_in[4];
    const float* w2    = (const float*)d_in[5];
    const float* b2    = (const float*)d_in[6];
    const float* gamma = (const float*)d_in[7];
    const float* beta  = (const float*)d_in[8];
    float* out = (float*)d_out;

    char* ws = (char*)d_ws;
    int*   counts   = (int*)(ws + 0);
    int*   cursors  = (int*)(ws + 64);
    int*   offs     = (int*)(ws + 128);
    int*   ntiles   = (int*)(ws + 256);
    int*   tile_e   = (int*)(ws + 512);
    int*   tile_m   = (int*)(ws + 1024);
    int*   sel      = (int*)(ws + 4096);
    float* wgt      = (float*)(ws + 4096 + 1 * 32768);
    int*   slot_of  = (int*)(ws + 4096 + 2 * 32768);
    int*   tok_list = (int*)(ws + 4096 + 3 * 32768);
    float* tok_w    = (float*)(ws + 4096 + 4 * 32768);
    unsigned short* Hbf = (unsigned short*)(ws + (1ull << 20));    //  8 MiB
    unsigned short* W1t = (unsigned short*)(ws + (9ull << 20));    // 64 MiB  (E,I,D) bf16
    unsigned short* W2t = (unsigned short*)(ws + (73ull << 20));   // 64 MiB  (E,D,I) bf16
    unsigned short* mid = (unsigned short*)(ws + (137ull << 20));  // 64 MiB  (2T,I) bf16
    float* slotbuf      = (float*)(ws + (201ull << 20));           // 32 MiB  (2T,D) f32

    hipMemsetAsync(counts, 0, 64, stream);
    gate_kernel<<<T_TOK, 256, 0, stream>>>(hs, gw, counts, sel, wgt);
    offsets_kernel<<<1, 64, 0, stream>>>(counts, offs, cursors, out + (size_t)T_TOK * D_DIM,
                                         tile_e, tile_m, ntiles);
    scatter_kernel<<<T_TOK / 256, 256, 0, stream>>>(sel, wgt, offs, cursors, tok_list, tok_w, slot_of);
    cvtH_kernel<<<(T_TOK * D_DIM / 8) / 256, 256, 0, stream>>>(hs, Hbf);
    transpose_cvt_kernel<<<dim3(I_DIM / 32, D_DIM / 32, E_EXP), dim3(32, 8), 0, stream>>>(w1, W1t, D_DIM, I_DIM);
    transpose_cvt_kernel<<<dim3(D_DIM / 32, I_DIM / 32, E_EXP), dim3(32, 8), 0, stream>>>(w2, W2t, I_DIM, D_DIM);
    moe_gemm_kernel<0><<<dim3(MAX_TILES, I_DIM / 128), 256, 0, stream>>>(
        Hbf, W1t, b1, counts, offs, tile_e, tile_m, ntiles, tok_list, tok_w, mid, nullptr);
    moe_gemm_kernel<1><<<dim3(MAX_TILES, D_DIM / 128), 256, 0, stream>>>(
        mid, W2t, b2, counts, offs, tile_e, tile_m, ntiles, tok_list, tok_w, nullptr, slotbuf);
    ln_kernel<<<T_TOK, 256, 0, stream>>>(hs, mask, slotbuf, slot_of, gamma, beta, out);
}

// Round 5
// 723.086 us; speedup vs baseline: 1.1304x; 1.0159x over previous
//
#include <hip/hip_runtime.h>
#include <hip/hip_bf16.h>
#include <math.h>

#define T_TOK 4096
#define D_DIM 1024
#define I_DIM 4096
#define E_EXP 8
#define MAX_TILES 72

typedef __attribute__((ext_vector_type(8))) short bf16x8;
typedef __attribute__((ext_vector_type(4))) float f32x4;

__device__ __forceinline__ unsigned short f2bf(float x) {
    unsigned int u = __float_as_uint(x);
    u += 0x7fffu + ((u >> 16) & 1u);   // RNE
    return (unsigned short)(u >> 16);
}

// async global->LDS, 16B per lane; lds dest = wave-uniform base + lane*16
__device__ __forceinline__ void glds16(const unsigned short* g, unsigned short* l) {
    __builtin_amdgcn_global_load_lds(
        (const __attribute__((address_space(1))) unsigned int*)g,
        (__attribute__((address_space(3))) unsigned int*)(unsigned int)(unsigned long long)(void*)l,
        16, 0, 0);
}

#define VMWAIT4 asm volatile("s_waitcnt vmcnt(4)" ::: "memory")
#define VMWAIT0 asm volatile("s_waitcnt vmcnt(0)" ::: "memory")

__device__ __forceinline__ void bar() {
    asm volatile("" ::: "memory");
    __builtin_amdgcn_s_barrier();
    asm volatile("" ::: "memory");
}

// ---------------- gate + H->bf16: logits (fp32), softmax, top-2, weights, Hbf write -------
__global__ void gate_kernel(const float* __restrict__ h, const float* __restrict__ gw,
                            int* __restrict__ counts, int* __restrict__ sel,
                            float* __restrict__ wgt, unsigned short* __restrict__ Hbf) {
    int t = blockIdx.x;
    int tid = threadIdx.x;
    const int d4 = tid * 4;                       // 256 threads x 4 = 1024 = D_DIM
    const float4 hv = *(const float4*)(h + (size_t)t * D_DIM + d4);
    union { unsigned short u[4]; ushort4 v; } o;
    o.u[0] = f2bf(hv.x); o.u[1] = f2bf(hv.y); o.u[2] = f2bf(hv.z); o.u[3] = f2bf(hv.w);
    *(ushort4*)(Hbf + (size_t)t * D_DIM + d4) = o.v;

    float acc[E_EXP];
#pragma unroll
    for (int e = 0; e < E_EXP; e++) {
        const float4 g = *(const float4*)(gw + e * D_DIM + d4);
        acc[e] = hv.x * g.x + hv.y * g.y + hv.z * g.z + hv.w * g.w;
    }
#pragma unroll
    for (int e = 0; e < E_EXP; e++)
        for (int off = 32; off > 0; off >>= 1) acc[e] += __shfl_down(acc[e], off, 64);
    __shared__ float red[4][E_EXP];
    int wave = tid >> 6, lane = tid & 63;
    if (lane == 0) {
#pragma unroll
        for (int e = 0; e < E_EXP; e++) red[wave][e] = acc[e];
    }
    __syncthreads();
    if (tid == 0) {
        float lg[E_EXP];
#pragma unroll
        for (int e = 0; e < E_EXP; e++) lg[e] = red[0][e] + red[1][e] + red[2][e] + red[3][e];
        float mx = lg[0];
#pragma unroll
        for (int e = 1; e < E_EXP; e++) mx = fmaxf(mx, lg[e]);
        float p[E_EXP];
#pragma unroll
        for (int e = 0; e < E_EXP; e++) p[e] = expf(lg[e] - mx);
        int i0 = 0; float b0 = p[0];
#pragma unroll
        for (int e = 1; e < E_EXP; e++) if (p[e] > b0) { b0 = p[e]; i0 = e; }
        int i1 = -1; float b1v = -1.f;
#pragma unroll
        for (int e = 0; e < E_EXP; e++) if (e != i0 && p[e] > b1v) { b1v = p[e]; i1 = e; }
        float den = b0 + b1v;
        sel[2 * t] = i0; sel[2 * t + 1] = i1;
        wgt[2 * t] = b0 / den; wgt[2 * t + 1] = b1v / den;
        atomicAdd(&counts[i0], 1);
        atomicAdd(&counts[i1], 1);
    }
}

// ---------------- offsets + cursors + aux loss + compacted tile table (BM=128) ----------------
__global__ void offsets_kernel(const int* __restrict__ counts, int* __restrict__ offs,
                               int* __restrict__ cursors, float* __restrict__ aux_out,
                               int* __restrict__ tile_e, int* __restrict__ tile_m,
                               int* __restrict__ ntiles) {
    if (blockIdx.x == 0 && threadIdx.x == 0) {
        int off = 0; float aux = 0.f; int nt = 0;
        for (int e = 0; e < E_EXP; e++) {
            offs[e] = off; off += counts[e]; cursors[e] = 0;
            float u = (float)counts[e] / (float)T_TOK;
            float d = u - 1.0f / (float)E_EXP;
            aux += d * d;
            for (int m0 = 0; m0 < counts[e]; m0 += 128) {
                tile_e[nt] = e; tile_m[nt] = m0; nt++;
            }
        }
        ntiles[0] = nt;
        aux_out[0] = aux / (float)E_EXP;
    }
}

// ---------------- scatter tokens into per-expert segments ----------------
__global__ void scatter_kernel(const int* __restrict__ sel, const float* __restrict__ wgt,
                               const int* __restrict__ offs, int* __restrict__ cursors,
                               int* __restrict__ tok_list, float* __restrict__ tok_w,
                               int* __restrict__ slot_of) {
    int t = blockIdx.x * 256 + threadIdx.x;
    if (t >= T_TOK) return;
#pragma unroll
    for (int k = 0; k < 2; k++) {
        int e = sel[2 * t + k];
        int pos = atomicAdd(&cursors[e], 1);
        int idx = offs[e] + pos;
        tok_list[idx] = t;
        tok_w[idx] = wgt[2 * t + k];
        slot_of[2 * t + k] = idx;
    }
}

// ---------------- fused weight transpose + fp32->bf16 for BOTH w1 and w2 ----------------
// z<8: w1 expert z  (R=D, C=I) -> W1t (I, D);  z>=8: w2 expert z-8 (R=I, C=D) -> W2t (D, I)
// 64x64 tile, float4 loads, ushort4 stores (128B-contiguous per 16-lane group).
__global__ void transpose_cvt2_kernel(const float* __restrict__ w1, const float* __restrict__ w2,
                                      unsigned short* __restrict__ W1t, unsigned short* __restrict__ W2t) {
    __shared__ float tile[64][65];
    const int z = blockIdx.y;
    const bool isW1 = (z < 8);
    const int e = isW1 ? z : z - 8;
    const int R = isW1 ? D_DIM : I_DIM;
    const int C = isW1 ? I_DIM : D_DIM;
    const float* s = (isW1 ? w1 : w2) + (size_t)e * R * C;
    unsigned short* d = (isW1 ? W1t : W2t) + (size_t)e * R * C;
    const int tpc = C >> 6;                       // tiles along C
    const int tr = blockIdx.x / tpc, tc = blockIdx.x % tpc;
    const int r0 = tr * 64, c0 = tc * 64;
    const int tid = threadIdx.x;
    const int rr = tid >> 4;                      // 0..15
    const int c4 = (tid & 15) * 4;                // 0..60
#pragma unroll
    for (int p = 0; p < 4; p++) {
        const float4 v = *(const float4*)(s + (size_t)(r0 + rr + 16 * p) * C + c0 + c4);
        tile[rr + 16 * p][c4]     = v.x;
        tile[rr + 16 * p][c4 + 1] = v.y;
        tile[rr + 16 * p][c4 + 2] = v.z;
        tile[rr + 16 * p][c4 + 3] = v.w;
    }
    __syncthreads();
#pragma unroll
    for (int p = 0; p < 4; p++) {
        const int oc = rr + 16 * p;               // output row (C-dim index)
        union { unsigned short u[4]; ushort4 v; } o;
#pragma unroll
        for (int k2 = 0; k2 < 4; k2++) o.u[k2] = f2bf(tile[c4 + k2][oc]);
        *(ushort4*)(d + (size_t)(c0 + oc) * R + r0 + c4) = o.v;
    }
}

// ---------------- grouped GEMM, 128x128 tile, 4 waves, 2-deep ring + counted vmcnt ----------
// m97-structure + zero-conflict XOR swizzle + issue-early staging (unchanged from r4, passed).
// MODE 0: mid = gelu(gather(Hbf) @ W1t^T + b1)   -> bf16 mid (2T x I)
// MODE 1: slotbuf = tok_w * (mid @ W2t^T + b2)   -> fp32 slotbuf (2T x D)
template <int MODE>
__launch_bounds__(256, 4)
__global__ void moe_gemm_kernel(const unsigned short* __restrict__ Abase,
                                const unsigned short* __restrict__ Bt,
                                const float* __restrict__ bias,
                                const int* __restrict__ counts, const int* __restrict__ offs,
                                const int* __restrict__ tile_e, const int* __restrict__ tile_m,
                                const int* __restrict__ ntiles,
                                const int* __restrict__ tok_list, const float* __restrict__ tok_w,
                                unsigned short* __restrict__ midout, float* __restrict__ slotbuf) {
    constexpr int K  = (MODE == 0) ? D_DIM : I_DIM;
    constexpr int N  = (MODE == 0) ? I_DIM : D_DIM;
    constexpr int NT = K / 32;     // K-tiles of BK=32

    __shared__ __align__(16) unsigned short lA[2][128 * 32];
    __shared__ __align__(16) unsigned short lB[2][128 * 32];

    const int nwg  = gridDim.x * gridDim.y;
    const int flat = blockIdx.y * gridDim.x + blockIdx.x;
    const int q8 = nwg >> 3, r8 = nwg & 7;
    const int xcd = flat & 7, pos = flat >> 3;
    const int id2 = (xcd < r8 ? xcd * (q8 + 1) : r8 * (q8 + 1) + (xcd - r8) * q8) + pos;
    const int tix = id2 / gridDim.y;
    const int nb  = id2 % gridDim.y;
    if (tix >= ntiles[0]) return;

    const int e   = tile_e[tix];
    const int m0  = tile_m[tix];
    const int Ne  = counts[e];
    const int seg = offs[e];
    const int n0  = nb * 128;

    const int tid  = threadIdx.x;
    const int w    = tid >> 6;
    const int lane = tid & 63;
    const int quad = lane >> 4;
    const int l15  = lane & 15;
    const int wm   = (w >> 1) * 64;    // wave row offset
    const int wn   = (w & 1) * 64;     // wave col offset

    const int lrow = lane >> 2;
    const int scol = (((lane & 3) ^ ((lane >> 3) & 3)) & 3) * 8;   // shorts
    const int rs   = (((quad ^ ((l15 >> 1) & 3)) & 3) * 8);        // shorts

    const unsigned short *gA0, *gA1;
    {
        int mr0 = m0 + w * 32 + lrow;
        int mr1 = mr0 + 16;
        int c0 = (mr0 < Ne) ? mr0 : 0;
        int c1 = (mr1 < Ne) ? mr1 : 0;
        size_t r0, r1;
        if (MODE == 0) { r0 = (size_t)tok_list[seg + c0] * K; r1 = (size_t)tok_list[seg + c1] * K; }
        else           { r0 = (size_t)(seg + c0) * K;         r1 = (size_t)(seg + c1) * K; }
        gA0 = Abase + r0 + scol;
        gA1 = Abase + r1 + scol;
    }
    const unsigned short* Bte = Bt + (size_t)e * N * K;
    const unsigned short* gB0 = Bte + (size_t)(n0 + w * 32 + lrow) * K + scol;
    const unsigned short* gB1 = gB0 + (size_t)16 * K;

    auto STAGE = [&](int t) {
        const int b = t & 1, off = t * 32;
        glds16(gA0 + off, &lA[b][(w * 32) * 32]);
        glds16(gA1 + off, &lA[b][(w * 32 + 16) * 32]);
        glds16(gB0 + off, &lB[b][(w * 32) * 32]);
        glds16(gB1 + off, &lB[b][(w * 32 + 16) * 32]);
    };

    f32x4 acc[4][4];
#pragma unroll
    for (int i = 0; i < 4; i++)
#pragma unroll
        for (int j = 0; j < 4; j++) acc[i][j] = (f32x4){0.f, 0.f, 0.f, 0.f};

    STAGE(0);
    for (int kt = 0; kt < NT; ++kt) {
        if (kt + 1 < NT) {
            STAGE(kt + 1);     // issue next tile FIRST: stays in flight across compute
            VMWAIT4;           // oldest 4 (= tile kt) landed; next 4 remain outstanding
        } else {
            VMWAIT0;           // final tile: full drain
        }
        bar();
        const unsigned short* LA = lA[kt & 1];
        const unsigned short* LB = lB[kt & 1];
        bf16x8 av[4], bv[4];
#pragma unroll
        for (int i = 0; i < 4; i++)
            av[i] = *(const bf16x8*)&LA[(wm + i * 16 + l15) * 32 + rs];
#pragma unroll
        for (int j = 0; j < 4; j++)
            bv[j] = *(const bf16x8*)&LB[(wn + j * 16 + l15) * 32 + rs];
        __builtin_amdgcn_s_setprio(1);
#pragma unroll
        for (int i = 0; i < 4; i++)
#pragma unroll
            for (int j = 0; j < 4; j++)
                acc[i][j] = __builtin_amdgcn_mfma_f32_16x16x32_bf16(av[i], bv[j], acc[i][j], 0, 0, 0);
        __builtin_amdgcn_s_setprio(0);
        bar();
    }

    // ---- epilogue ----
    const float* be = bias + (size_t)e * N;
#pragma unroll
    for (int i = 0; i < 4; i++) {
        const int mbase = m0 + wm + i * 16 + quad * 4;
#pragma unroll
        for (int j = 0; j < 4; j++) {
            const int n = n0 + wn + j * 16 + l15;
            const float bvl = be[n];
#pragma unroll
            for (int r = 0; r < 4; r++) {
                const int m = mbase + r;
                if (m < Ne) {
                    float v = acc[i][j][r] + bvl;
                    if (MODE == 0) {
                        v = 0.5f * v * (1.0f + erff(v * 0.70710678118654752f));
                        midout[(size_t)(seg + m) * N + n] = f2bf(v);
                    } else {
                        slotbuf[(size_t)(seg + m) * N + n] = tok_w[seg + m] * v;
                    }
                }
            }
        }
    }
}

// ---------------- residual + mask + LayerNorm ----------------
__global__ void ln_kernel(const float* __restrict__ hs, const float* __restrict__ mask,
                          const float* __restrict__ slotbuf, const int* __restrict__ slot_of,
                          const float* __restrict__ gamma, const float* __restrict__ beta,
                          float* __restrict__ outp) {
    int t = blockIdx.x, tid = threadIdx.x;
    int s0 = slot_of[2 * t], s1 = slot_of[2 * t + 1];
    float mk = mask[t];
    const float4* hr = (const float4*)(hs + (size_t)t * D_DIM);
    const float4* p0 = (const float4*)(slotbuf + (size_t)s0 * D_DIM);
    const float4* p1 = (const float4*)(slotbuf + (size_t)s1 * D_DIM);
    float4 hv = hr[tid], a = p0[tid], b = p1[tid];
    float x0 = hv.x + mk * (a.x + b.x);
    float x1 = hv.y + mk * (a.y + b.y);
    float x2 = hv.z + mk * (a.z + b.z);
    float x3 = hv.w + mk * (a.w + b.w);
    float sum = x0 + x1 + x2 + x3;
    float sq = x0 * x0 + x1 * x1 + x2 * x2 + x3 * x3;
    for (int off = 32; off > 0; off >>= 1) {
        sum += __shfl_down(sum, off, 64);
        sq += __shfl_down(sq, off, 64);
    }
    __shared__ float rsum[4], rsq[4];
    __shared__ float mu_s, rstd_s;
    int wave = tid >> 6, lane = tid & 63;
    if (lane == 0) { rsum[wave] = sum; rsq[wave] = sq; }
    __syncthreads();
    if (tid == 0) {
        float s = rsum[0] + rsum[1] + rsum[2] + rsum[3];
        float q = rsq[0] + rsq[1] + rsq[2] + rsq[3];
        float mu = s / (float)D_DIM;
        float var = q / (float)D_DIM - mu * mu;
        mu_s = mu; rstd_s = rsqrtf(var + 1e-5f);
    }
    __syncthreads();
    float mu = mu_s, rstd = rstd_s;
    const float4* g4 = (const float4*)gamma;
    const float4* b4 = (const float4*)beta;
    float4 g = g4[tid], bb = b4[tid];
    float4 o;
    o.x = (x0 - mu) * rstd * g.x + bb.x;
    o.y = (x1 - mu) * rstd * g.y + bb.y;
    o.z = (x2 - mu) * rstd * g.z + bb.z;
    o.w = (x3 - mu) * rstd * g.w + bb.w;
    ((float4*)(outp + (size_t)t * D_DIM))[tid] = o;
}

extern "C" void kernel_launch(void* const* d_in, const int* in_sizes, int n_in,
                              void* d_out, int out_size, void* d_ws, size_t ws_size,
                              hipStream_t stream) {
    const float* hs    = (const float*)d_in[0];
    const float* mask  = (const float*)d_in[1];
    const float* gw    = (const float*)d_in[2];
    const float* w1    = (const float*)d_in[3];
    const float* b1    = (const float*)d_in[4];
    const float* w2    = (const float*)d_in[5];
    const float* b2    = (const float*)d_in[6];
    const float* gamma = (const float*)d_in[7];
    const float* beta  = (const float*)d_in[8];
    float* out = (float*)d_out;

    char* ws = (char*)d_ws;
    int*   counts   = (int*)(ws + 0);
    int*   cursors  = (int*)(ws + 64);
    int*   offs     = (int*)(ws + 128);
    int*   ntiles   = (int*)(ws + 256);
    int*   tile_e   = (int*)(ws + 512);
    int*   tile_m   = (int*)(ws + 1024);
    int*   sel      = (int*)(ws + 4096);
    float* wgt      = (float*)(ws + 4096 + 1 * 32768);
    int*   slot_of  = (int*)(ws + 4096 + 2 * 32768);
    int*   tok_list = (int*)(ws + 4096 + 3 * 32768);
    float* tok_w    = (float*)(ws + 4096 + 4 * 32768);
    unsigned short* Hbf = (unsigned short*)(ws + (1ull << 20));    //  8 MiB
    unsigned short* W1t = (unsigned short*)(ws + (9ull << 20));    // 64 MiB  (E,I,D) bf16
    unsigned short* W2t = (unsigned short*)(ws + (73ull << 20));   // 64 MiB  (E,D,I) bf16
    unsigned short* mid = (unsigned short*)(ws + (137ull << 20));  // 64 MiB  (2T,I) bf16
    float* slotbuf      = (float*)(ws + (201ull << 20));           // 32 MiB  (2T,D) f32

    hipMemsetAsync(counts, 0, 64, stream);
    gate_kernel<<<T_TOK, 256, 0, stream>>>(hs, gw, counts, sel, wgt, Hbf);
    offsets_kernel<<<1, 64, 0, stream>>>(counts, offs, cursors, out + (size_t)T_TOK * D_DIM,
                                         tile_e, tile_m, ntiles);
    scatter_kernel<<<T_TOK / 256, 256, 0, stream>>>(sel, wgt, offs, cursors, tok_list, tok_w, slot_of);
    transpose_cvt2_kernel<<<dim3(1024, 16), 256, 0, stream>>>(w1, w2, W1t, W2t);
    moe_gemm_kernel<0><<<dim3(MAX_TILES, I_DIM / 128), 256, 0, stream>>>(
        Hbf, W1t, b1, counts, offs, tile_e, tile_m, ntiles, tok_list, tok_w, mid, nullptr);
    moe_gemm_kernel<1><<<dim3(MAX_TILES, D_DIM / 128), 256, 0, stream>>>(
        mid, W2t, b2, counts, offs, tile_e, tile_m, ntiles, tok_list, tok_w, nullptr, slotbuf);
    ln_kernel<<<T_TOK, 256, 0, stream>>>(hs, mask, slotbuf, slot_of, gamma, beta, out);
}